// Round 1
// baseline (112.945 us; speedup 1.0000x reference)
//
#include <hip/hip_runtime.h>
#include <cstdint>

typedef unsigned int u32;

// ---------------------------------------------------------------------------
// Threefry-2x32 (20 rounds), matching jax._src.prng.threefry2x32.
// PRNG derivation used here assumes jax_threefry_partitionable=True
// (default since JAX 0.5.0):
//   split(key, n)[i]           = threefry2x32(key, (0, i))           (full pair)
//   random_bits(key,32,shape)e = r0 ^ r1 of threefry2x32(key, (0,e)) (64-bit iota)
// If this round fails with absmax ~= 1.0 (mask mismatch), switch to LEGACY:
//   split(key,n)[i] = (r0,r1) of threefry2x32(key, (i, n+i))
//   bits over n elems: e<n/2 -> r0 of TF(key,(e,e+n/2)); else r1 of TF(key,(e-n/2,e))
//   scalar uniform bits = r0 of TF(key,(0,0))
// ---------------------------------------------------------------------------
#define TF_R4(a,b,r1,r2,r3,r4) \
  a += b; b = (b<<r1)|(b>>(32-r1)); b ^= a; \
  a += b; b = (b<<r2)|(b>>(32-r2)); b ^= a; \
  a += b; b = (b<<r3)|(b>>(32-r3)); b ^= a; \
  a += b; b = (b<<r4)|(b>>(32-r4)); b ^= a;

__host__ __device__ inline void tf2x32(u32 k0, u32 k1, u32& x0, u32& x1) {
  const u32 k2 = k0 ^ k1 ^ 0x1BD11BDAu;
  u32 a = x0 + k0, b = x1 + k1;
  TF_R4(a,b,13,15,26,6)   a += k1; b += k2 + 1u;
  TF_R4(a,b,17,29,16,24)  a += k2; b += k0 + 2u;
  TF_R4(a,b,13,15,26,6)   a += k0; b += k1 + 3u;
  TF_R4(a,b,17,29,16,24)  a += k1; b += k2 + 4u;
  TF_R4(a,b,13,15,26,6)   a += k2; b += k0 + 5u;
  x0 = a; x1 = b;
}

__host__ __device__ inline float u01(u32 bits) {
  union { u32 u; float f; } c; c.u = (bits >> 9) | 0x3f800000u;
  return c.f - 1.0f;
}
// scalar uniform bits under partitionable semantics: counter (0,0), xor halves
__host__ __device__ inline u32 rbits_scalar(u32 k0, u32 k1) {
  u32 a = 0, b = 0; tf2x32(k0, k1, a, b); return a ^ b;
}

// problem constants
#define BATCH   512
#define HW      224
#define S       50176     /* 224*224 */
#define S4      12544     /* S/4 */
#define NTOT    25690112  /* 512*50176 */
#define N4      6422528   /* NTOT/4 */

struct SP { float thr; int hs, he, wss, wee, doit; int pad0, pad1; };

// ---------------------------------------------------------------------------
// Kernel 1: per-sample stats -> erase-box params
// ---------------------------------------------------------------------------
__global__ __launch_bounds__(256) void k_stats(const float* __restrict__ x,
                                               SP* __restrict__ sp,
                                               float factor, u32 ks0, u32 ks1) {
  const int b = blockIdx.x;
  const int t = threadIdx.x;
  const float4* xm = (const float4*)(x + (size_t)b * S);

  // pass A: max + first argmax + min
  float vmax = -1.0f; int imax = 0x7fffffff; float vmin = 2.0f;
  for (int i = t; i < S4; i += 256) {
    float4 v = xm[i];
    int base = i * 4;
    if (v.x > vmax) { vmax = v.x; imax = base; }
    if (v.y > vmax) { vmax = v.y; imax = base + 1; }
    if (v.z > vmax) { vmax = v.z; imax = base + 2; }
    if (v.w > vmax) { vmax = v.w; imax = base + 3; }
    vmin = fminf(vmin, fminf(fminf(v.x, v.y), fminf(v.z, v.w)));
  }
  __shared__ float sv[256]; __shared__ int si[256]; __shared__ float sn[256];
  sv[t] = vmax; si[t] = imax; sn[t] = vmin;
  __syncthreads();
  for (int s = 128; s > 0; s >>= 1) {
    if (t < s) {
      float v2 = sv[t + s]; int i2 = si[t + s];
      if (v2 > sv[t] || (v2 == sv[t] && i2 < si[t])) { sv[t] = v2; si[t] = i2; }
      sn[t] = fminf(sn[t], sn[t + s]);
    }
    __syncthreads();
  }

  __shared__ float s_thr;
  __shared__ int sbox[4]; // miny, maxy, minx, maxx
  if (t == 0) {
    float mx = sv[0], mn = sn[0];
    // thr = mx - (mx - mn) * factor  -- NO fma contraction (match XLA)
    s_thr = __fsub_rn(mx, __fmul_rn(__fsub_rn(mx, mn), factor));
    sbox[0] = HW; sbox[1] = -1; sbox[2] = HW; sbox[3] = -1;
  }
  __syncthreads();
  const float thr = s_thr;

  // pass B: bounding box of prop = x > thr
  int miny = HW, maxy = -1, minx = HW, maxx = -1;
  for (int i = t; i < S4; i += 256) {
    float4 v = xm[i];
    int base = i * 4;
    int y = base / HW; int xc = base % HW;  // 224 % 4 == 0 -> same row
    bool p0 = v.x > thr, p1 = v.y > thr, p2 = v.z > thr, p3 = v.w > thr;
    if (p0 | p1 | p2 | p3) { miny = min(miny, y); maxy = max(maxy, y); }
    if (p0) { minx = min(minx, xc);     maxx = max(maxx, xc); }
    if (p1) { minx = min(minx, xc + 1); maxx = max(maxx, xc + 1); }
    if (p2) { minx = min(minx, xc + 2); maxx = max(maxx, xc + 2); }
    if (p3) { minx = min(minx, xc + 3); maxx = max(maxx, xc + 3); }
  }
  atomicMin(&sbox[0], miny); atomicMax(&sbox[1], maxy);
  atomicMin(&sbox[2], minx); atomicMax(&sbox[3], maxx);
  __syncthreads();

  if (t == 0) {
    int mny = sbox[0], mxy = sbox[1], mnx = sbox[2], mxx = sbox[3];
    bool any = (mxy >= 0);
    int mh2 = (mxy - mny) / 2;  // when any: >=0 so trunc == floor
    int mw2 = (mxx - mnx) / 2;
    bool valid = any && (mh2 > 4) && (mw2 > 4);

    // per-sample keys (partitionable / fold-like split)
    u32 kb0 = 0, kb1 = (u32)b; tf2x32(ks0, ks1, kb0, kb1);   // keys[b]
    u32 ka0 = 0, ka1 = 0; tf2x32(kb0, kb1, ka0, ka1);        // k_apply
    u32 kh0 = 0, kh1 = 1; tf2x32(kb0, kb1, kh0, kh1);        // k_h
    u32 kw0 = 0, kw1 = 2; tf2x32(kb0, kb1, kw0, kw1);        // k_w
    float ua = u01(rbits_scalar(ka0, ka1));
    float uh = u01(rbits_scalar(kh0, kh1));
    float uw = u01(rbits_scalar(kw0, kw1));
    bool apply = ua < 0.5f;

    int c  = si[0];
    int cy = c / HW, cx = c % HW;
    int h = 4 + (int)(uh * (float)max(mh2 - 4, 1));
    int w = 4 + (int)(uw * (float)max(mw2 - 4, 1));

    SP p;
    p.thr = thr;
    p.hs = max(cy - h, 0); p.he = min(cy + h, HW);
    p.wss = max(cx - w, 0); p.wee = min(cx + w, HW);
    p.doit = (apply && valid) ? 1 : 0;
    p.pad0 = 0; p.pad1 = 0;
    sp[b] = p;
  }
}

// ---------------------------------------------------------------------------
// Kernel 2: elementwise out/mask with threefry bernoulli noise
// ---------------------------------------------------------------------------
__global__ __launch_bounds__(256) void k_apply(const float* __restrict__ x,
                                               const SP* __restrict__ sp,
                                               float* __restrict__ out,
                                               float* __restrict__ mout,
                                               u32 kn0, u32 kn1) {
  const int idx4 = blockIdx.x * 256 + threadIdx.x;
  if (idx4 >= N4) return;
  const int b   = idx4 / S4;
  const int rem = idx4 % S4;
  const int y   = rem / 56;        // 56 float4 per row
  const int x0  = (rem % 56) * 4;

  const SP p = sp[b];
  const float4 xv = ((const float4*)x)[idx4];
  const float vv[4] = { xv.x, xv.y, xv.z, xv.w };
  const u32 ebase = (u32)idx4 * 4u;

  float o[4], m[4];
#pragma unroll
  for (int j = 0; j < 4; ++j) {
    u32 c0 = 0u, c1 = ebase + (u32)j;
    tf2x32(kn0, kn1, c0, c1);
    float u = u01(c0 ^ c1);
    // inp = 0.6*x + 0.2  -- NO fma contraction
    float inp = __fadd_rn(__fmul_rn(0.6f, vv[j]), 0.2f);
    float kp  = fminf(fmaxf(__fsub_rn(1.0f, inp), 0.0f), 1.0f);
    bool pm   = u < kp;                 // bernoulli keep
    int  xx   = x0 + j;
    bool prop = vv[j] > p.thr;
    bool erase = prop && (y > p.hs) && (y < p.he) &&
                 (xx > p.wss) && (xx < p.wee) && (y > 0) && (xx > 0);
    bool mz = (p.doit != 0) && erase;   // mask == 0 here
    m[j] = mz ? 0.0f : 1.0f;
    o[j] = mz ? (pm ? inp : 0.0f) : inp;  // inp*noise, exact
  }
  ((float4*)out)[idx4]  = make_float4(o[0], o[1], o[2], o[3]);
  ((float4*)mout)[idx4] = make_float4(m[0], m[1], m[2], m[3]);
}

// ---------------------------------------------------------------------------
extern "C" void kernel_launch(void* const* d_in, const int* in_sizes, int n_in,
                              void* d_out, int out_size, void* d_ws, size_t ws_size,
                              hipStream_t stream) {
  const float* x = (const float*)d_in[0];
  float* out  = (float*)d_out;
  float* mout = out + NTOT;
  SP* sp = (SP*)d_ws;

  // host-side (pure CPU, capture-safe) key derivation: root = key(42) = (0,42)
  u32 kf0 = 0, kf1 = 0; tf2x32(0u, 42u, kf0, kf1);   // k_factor = split[0]
  u32 ks0 = 0, ks1 = 1; tf2x32(0u, 42u, ks0, ks1);   // k_samples = split[1]
  u32 kn0 = 0, kn1 = 2; tf2x32(0u, 42u, kn0, kn1);   // k_noise  = split[2]
  float factor = fmaxf(0.0f, u01(rbits_scalar(kf0, kf1)) * 0.5f);

  hipLaunchKernelGGL(k_stats, dim3(BATCH), dim3(256), 0, stream,
                     x, sp, factor, ks0, ks1);
  hipLaunchKernelGGL(k_apply, dim3(N4 / 256), dim3(256), 0, stream,
                     x, sp, out, mout, kn0, kn1);
}

// Round 2
// 109.259 us; speedup vs baseline: 1.0337x; 1.0337x over previous
//
#include <hip/hip_runtime.h>
#include <cstdint>

typedef unsigned int u32;

// ---------------------------------------------------------------------------
// Threefry-2x32 (20 rounds) — validated bit-exact vs JAX in round 1
// (jax_threefry_partitionable=True semantics).
//   split(key, n)[i]           = threefry2x32(key, (0, i))
//   random_bits(key,32,shape)e = r0 ^ r1 of threefry2x32(key, (0, e))
// ---------------------------------------------------------------------------
#define TF_R4(a,b,r1,r2,r3,r4) \
  a += b; b = (b<<r1)|(b>>(32-r1)); b ^= a; \
  a += b; b = (b<<r2)|(b>>(32-r2)); b ^= a; \
  a += b; b = (b<<r3)|(b>>(32-r3)); b ^= a; \
  a += b; b = (b<<r4)|(b>>(32-r4)); b ^= a;

__host__ __device__ inline void tf2x32(u32 k0, u32 k1, u32& x0, u32& x1) {
  const u32 k2 = k0 ^ k1 ^ 0x1BD11BDAu;
  u32 a = x0 + k0, b = x1 + k1;
  TF_R4(a,b,13,15,26,6)   a += k1; b += k2 + 1u;
  TF_R4(a,b,17,29,16,24)  a += k2; b += k0 + 2u;
  TF_R4(a,b,13,15,26,6)   a += k0; b += k1 + 3u;
  TF_R4(a,b,17,29,16,24)  a += k1; b += k2 + 4u;
  TF_R4(a,b,13,15,26,6)   a += k2; b += k0 + 5u;
  x0 = a; x1 = b;
}

__host__ __device__ inline float u01(u32 bits) {
  union { u32 u; float f; } c; c.u = (bits >> 9) | 0x3f800000u;
  return c.f - 1.0f;
}
__host__ __device__ inline u32 rbits_scalar(u32 k0, u32 k1) {
  u32 a = 0, b = 0; tf2x32(k0, k1, a, b); return a ^ b;
}

// problem constants
#define BATCH   512
#define HW      224
#define S       50176     /* 224*224 */
#define S4      12544     /* S/4 */
#define NTOT    25690112  /* 512*50176 */
#define TPB     896       /* 14 waves; S4 / TPB == 14 exactly */
#define PER     14        /* float4 per thread */
#define NW      14        /* waves per block */

// ---------------------------------------------------------------------------
// Fused kernel: one block per sample.
//   regs <- sample (single HBM read)
//   pass A: max / first-argmax / min   (regs, shuffle reduce)
//   pass B: bbox of prop = x > thr      (regs, shuffle reduce)
//   pass C: out/mask write; threefry only for erased elements (rare path)
// ---------------------------------------------------------------------------
__global__ __launch_bounds__(TPB) void k_fused(const float* __restrict__ x,
                                               float* __restrict__ out,
                                               float factor,
                                               u32 ks0, u32 ks1,
                                               u32 kn0, u32 kn1) {
  const int b    = blockIdx.x;
  const int t    = threadIdx.x;
  const int lane = t & 63, wid = t >> 6;
  const float4* __restrict__ xs = (const float4*)(x + (size_t)b * S);
  float4* __restrict__ os = (float4*)(out + (size_t)b * S);
  float4* __restrict__ ms = (float4*)(out + (size_t)NTOT + (size_t)b * S);

  // ---- load sample into registers (the only HBM read of x) ----
  float4 v[PER];
#pragma unroll
  for (int k = 0; k < PER; ++k) v[k] = xs[k * TPB + t];

  // ---- pass A: max + first argmax + min ----
  float vmax = -1.0f; int imax = 0x7fffffff; float vmin = 2.0f;
#pragma unroll
  for (int k = 0; k < PER; ++k) {
    const int base = (k * TPB + t) * 4;
    const float4 vv = v[k];
    if (vv.x > vmax) { vmax = vv.x; imax = base; }
    if (vv.y > vmax) { vmax = vv.y; imax = base + 1; }
    if (vv.z > vmax) { vmax = vv.z; imax = base + 2; }
    if (vv.w > vmax) { vmax = vv.w; imax = base + 3; }
    vmin = fminf(vmin, fminf(fminf(vv.x, vv.y), fminf(vv.z, vv.w)));
  }
  for (int off = 32; off; off >>= 1) {
    float v2 = __shfl_xor(vmax, off);
    int   i2 = __shfl_xor(imax, off);
    float n2 = __shfl_xor(vmin, off);
    if (v2 > vmax || (v2 == vmax && i2 < imax)) { vmax = v2; imax = i2; }
    vmin = fminf(vmin, n2);
  }
  __shared__ float pmax[NW]; __shared__ int pidx[NW]; __shared__ float pmin[NW];
  __shared__ float s_thr;
  if (lane == 0) { pmax[wid] = vmax; pidx[wid] = imax; pmin[wid] = vmin; }
  __syncthreads();
  if (t == 0) {
    float mx = pmax[0]; int ix = pidx[0]; float mn = pmin[0];
    for (int wI = 1; wI < NW; ++wI) {
      if (pmax[wI] > mx || (pmax[wI] == mx && pidx[wI] < ix)) { mx = pmax[wI]; ix = pidx[wI]; }
      mn = fminf(mn, pmin[wI]);
    }
    // thr = mx - (mx - mn) * factor  -- no fma contraction (match XLA)
    s_thr = __fsub_rn(mx, __fmul_rn(__fsub_rn(mx, mn), factor));
    pidx[0] = ix;  // stash global argmax
  }
  __syncthreads();
  const float thr = s_thr;

  // ---- pass B: bbox of prop (from registers) ----
  int miny = HW, maxy = -1, minx = HW, maxx = -1;
#pragma unroll
  for (int k = 0; k < PER; ++k) {
    const int base = (k * TPB + t) * 4;
    const int y = base / HW, xc = base % HW;   // 224%4==0 -> float4 within one row
    const float4 vv = v[k];
    bool p0 = vv.x > thr, p1 = vv.y > thr, p2 = vv.z > thr, p3 = vv.w > thr;
    if (p0 | p1 | p2 | p3) { miny = min(miny, y); maxy = max(maxy, y); }
    if (p0) { minx = min(minx, xc);     maxx = max(maxx, xc); }
    if (p1) { minx = min(minx, xc + 1); maxx = max(maxx, xc + 1); }
    if (p2) { minx = min(minx, xc + 2); maxx = max(maxx, xc + 2); }
    if (p3) { minx = min(minx, xc + 3); maxx = max(maxx, xc + 3); }
  }
  for (int off = 32; off; off >>= 1) {
    miny = min(miny, __shfl_xor(miny, off));
    maxy = max(maxy, __shfl_xor(maxy, off));
    minx = min(minx, __shfl_xor(minx, off));
    maxx = max(maxx, __shfl_xor(maxx, off));
  }
  __shared__ int bb0[NW], bb1[NW], bb2[NW], bb3[NW];
  __shared__ int sbox[5];  // hs, he, ws, we, doit
  if (lane == 0) { bb0[wid] = miny; bb1[wid] = maxy; bb2[wid] = minx; bb3[wid] = maxx; }
  __syncthreads();
  if (t == 0) {
    int mny = bb0[0], mxy = bb1[0], mnx = bb2[0], mxx = bb3[0];
    for (int wI = 1; wI < NW; ++wI) {
      mny = min(mny, bb0[wI]); mxy = max(mxy, bb1[wI]);
      mnx = min(mnx, bb2[wI]); mxx = max(mxx, bb3[wI]);
    }
    bool any = (mxy >= 0);
    int mh2 = (mxy - mny) / 2;
    int mw2 = (mxx - mnx) / 2;
    bool valid = any && (mh2 > 4) && (mw2 > 4);

    u32 kb0 = 0, kb1 = (u32)b; tf2x32(ks0, ks1, kb0, kb1);   // keys[b]
    u32 ka0 = 0, ka1 = 0; tf2x32(kb0, kb1, ka0, ka1);        // k_apply
    u32 kh0 = 0, kh1 = 1; tf2x32(kb0, kb1, kh0, kh1);        // k_h
    u32 kw0 = 0, kw1 = 2; tf2x32(kb0, kb1, kw0, kw1);        // k_w
    bool apply = u01(rbits_scalar(ka0, ka1)) < 0.5f;
    float uh = u01(rbits_scalar(kh0, kh1));
    float uw = u01(rbits_scalar(kw0, kw1));

    int c = pidx[0], cy = c / HW, cx = c % HW;
    int h = 4 + (int)(uh * (float)max(mh2 - 4, 1));
    int w = 4 + (int)(uw * (float)max(mw2 - 4, 1));
    sbox[0] = max(cy - h, 0); sbox[1] = min(cy + h, HW);
    sbox[2] = max(cx - w, 0); sbox[3] = min(cx + w, HW);
    sbox[4] = (apply && valid) ? 1 : 0;
  }
  __syncthreads();
  const int hs = sbox[0], he = sbox[1], wss = sbox[2], wee = sbox[3];
  const int doit = sbox[4];
  const u32 eoff = (u32)b * (u32)S;   // global element offset of this sample

  // ---- pass C: write out/mask; defer threefry to rare path ----
  unsigned long long need = 0ull;     // bit (k*4+j): element needs RNG
#pragma unroll
  for (int k = 0; k < PER; ++k) {
    const int i = k * TPB + t;
    const int base = i * 4;
    const int y = base / HW, x0 = base % HW;
    const float4 vv = v[k];
    const bool yin = doit && (y > hs) && (y < he) && (y > 0);
    float o[4], m[4];
#pragma unroll
    for (int j = 0; j < 4; ++j) {
      const float val = (j == 0) ? vv.x : (j == 1) ? vv.y : (j == 2) ? vv.z : vv.w;
      // inp = 0.6*x + 0.2 -- no fma contraction
      const float inp = __fadd_rn(__fmul_rn(0.6f, val), 0.2f);
      const int xx = x0 + j;
      const bool mz = yin && (val > thr) && (xx > wss) && (xx < wee) && (xx > 0);
      m[j] = mz ? 0.0f : 1.0f;
      o[j] = inp;                     // provisional; rare path may zero it
      if (mz) need |= 1ull << (k * 4 + j);
    }
    os[i] = make_float4(o[0], o[1], o[2], o[3]);
    ms[i] = make_float4(m[0], m[1], m[2], m[3]);
  }

  // rare path: erased elements only — bernoulli via threefry, zero the drops
  while (need) {
    const int bit = __ffsll((unsigned long long)need) - 1;
    need &= need - 1;
    const int k = bit >> 2, j = bit & 3;
    const int base = (k * TPB + t) * 4 + j;
    const float val = ((const float*)xs)[base];          // L2/L3 hit
    const float inp = __fadd_rn(__fmul_rn(0.6f, val), 0.2f);
    const float kp  = fminf(fmaxf(__fsub_rn(1.0f, inp), 0.0f), 1.0f);
    u32 c0 = 0u, c1 = eoff + (u32)base;
    tf2x32(kn0, kn1, c0, c1);
    if (!(u01(c0 ^ c1) < kp))
      ((float*)os)[base] = 0.0f;                          // inp * 0
  }
}

// ---------------------------------------------------------------------------
extern "C" void kernel_launch(void* const* d_in, const int* in_sizes, int n_in,
                              void* d_out, int out_size, void* d_ws, size_t ws_size,
                              hipStream_t stream) {
  const float* x = (const float*)d_in[0];
  float* out = (float*)d_out;

  // host-side key derivation: root = key(42) = (0,42)
  u32 kf0 = 0, kf1 = 0; tf2x32(0u, 42u, kf0, kf1);   // k_factor = split[0]
  u32 ks0 = 0, ks1 = 1; tf2x32(0u, 42u, ks0, ks1);   // k_samples = split[1]
  u32 kn0 = 0, kn1 = 2; tf2x32(0u, 42u, kn0, kn1);   // k_noise  = split[2]
  float factor = fmaxf(0.0f, u01(rbits_scalar(kf0, kf1)) * 0.5f);

  hipLaunchKernelGGL(k_fused, dim3(BATCH), dim3(TPB), 0, stream,
                     x, out, factor, ks0, ks1, kn0, kn1);
}